// Round 2
// baseline (90.584 us; speedup 1.0000x reference)
//
#include <hip/hip_runtime.h>

// Problem constants (B=16, H=512, W=512, C=3)
#define BDIM 16
#define HDIM 512
#define WDIM 512
#define CDIM 3

typedef float f32x2 __attribute__((ext_vector_type(2)));

// Packed low-alignment vector types (frame pixel stride = 12 B).
struct __attribute__((aligned(4))) pf4 { float x, y, z, w; };
struct __attribute__((aligned(4))) pf2 { float x, y; };

struct Taps {
    pf4 a0; pf2 b0;   // row0: tl0 tl1 tl2 tr0 | tr1 tr2
    pf4 a1; pf2 b1;   // row1: bl0 bl1 bl2 br0 | br1 br2
    float ax, ay;
};

__device__ __forceinline__ Taps bilinear_load(
    const float* __restrict__ img, float qy, float qx)
{
    float fy = fminf(fmaxf(floorf(qy), 0.0f), (float)(HDIM - 2));
    float fx = fminf(fmaxf(floorf(qx), 0.0f), (float)(WDIM - 2));
    Taps tp;
    tp.ay = fminf(fmaxf(qy - fy, 0.0f), 1.0f);
    tp.ax = fminf(fmaxf(qx - fx, 0.0f), 1.0f);
    int iy = (int)fy;
    int ix = (int)fx;
    const float* r0 = img + ((size_t)iy * WDIM + ix) * CDIM;
    const float* r1 = r0 + WDIM * CDIM;
    tp.a0 = *reinterpret_cast<const pf4*>(r0);
    tp.b0 = *reinterpret_cast<const pf2*>(r0 + 4);
    tp.a1 = *reinterpret_cast<const pf4*>(r1);
    tp.b1 = *reinterpret_cast<const pf2*>(r1 + 4);
    return tp;
}

__device__ __forceinline__ void bilinear_eval(const Taps& t, float g[3])
{
    float tl[3] = {t.a0.x, t.a0.y, t.a0.z};
    float tr[3] = {t.a0.w, t.b0.x, t.b0.y};
    float bl[3] = {t.a1.x, t.a1.y, t.a1.z};
    float br[3] = {t.a1.w, t.b1.x, t.b1.y};
#pragma unroll
    for (int c = 0; c < CDIM; ++c) {
        float top = tl[c] + t.ax * (tr[c] - tl[c]);
        float bot = bl[c] + t.ax * (br[c] - bl[c]);
        g[c] = top + t.ay * (bot - top);
    }
}

// R16: revert to R14 structure (lane-adjacent gather footprint, dual chain
// 8 batches apart, strided dword stores, 8192x256). R15 post-mortem: 2px
// lane stride doubled per-instruction tap footprint (768B -> 1536B/wave)
// and regressed 13%; nt STORES raised WRITE_SIZE with no fetch benefit.
// New in R16:
//  - flow/vis loads are __builtin_nontemporal_load: 75 MB of single-touch
//    streaming data no longer evicts the 100 MB frame set from the 256 MB
//    LLC. Frames are the latency-critical gather target; keeping them
//    LLC-resident cuts tap latency (~900cy HBM -> LLC-hit).
//  - tind scalarized via readfirstlane (bA/bB are block-uniform: blocks
//    cover 256-px aligned chunks, batch = 2^18 px).
__global__ __launch_bounds__(256) void warp_interp_kernel(
    const float* __restrict__ frames0,  // [B,H,W,3]
    const float* __restrict__ flow0,    // [B,H,W,2]
    const float* __restrict__ vis0,     // [B,H,W,1]
    const float* __restrict__ frames1,  // [B,H,W,3]
    const float* __restrict__ flow1,    // [B,H,W,2]
    const float* __restrict__ vis1,     // [B,H,W,1]
    const float* __restrict__ tind,     // [B]
    float* __restrict__ out)            // [B,H,W,3]
{
    const int bid = blockIdx.x;
    const int swz = (bid & 7) * 1024 + (bid >> 3);  // bijective: 8192 = 8*1024
    const int idx = swz * 256 + threadIdx.x;        // 0 .. 2097151
    const int STRIDE = 8192 * 256;                  // 2097152 px = 8 batches

    const size_t pA = (size_t)idx;
    const size_t pB = pA + STRIDE;

    const int xA = (int)(pA & (WDIM - 1));
    const int yA = (int)((pA >> 9) & (HDIM - 1));
    const int bA = (int)(pA >> 18);
    const int xB = (int)(pB & (WDIM - 1));
    const int yB = (int)((pB >> 9) & (HDIM - 1));
    const int bB = (int)(pB >> 18);

    // Phase 1: stream loads for both pixels (nontemporal: zero reuse,
    // keep them out of the LLC so the frames stay resident).
    f32x2 f0A = __builtin_nontemporal_load(
        reinterpret_cast<const f32x2*>(flow0 + 2 * pA));
    f32x2 f1A = __builtin_nontemporal_load(
        reinterpret_cast<const f32x2*>(flow1 + 2 * pA));
    f32x2 f0B = __builtin_nontemporal_load(
        reinterpret_cast<const f32x2*>(flow0 + 2 * pB));
    f32x2 f1B = __builtin_nontemporal_load(
        reinterpret_cast<const f32x2*>(flow1 + 2 * pB));
    float v0A = __builtin_nontemporal_load(vis0 + pA);
    float v1A = __builtin_nontemporal_load(vis1 + pA);
    float v0B = __builtin_nontemporal_load(vis0 + pB);
    float v1B = __builtin_nontemporal_load(vis1 + pB);

    // Block-uniform batch indices -> scalar loads of tind.
    const int bAu = __builtin_amdgcn_readfirstlane(bA);
    const int bBu = __builtin_amdgcn_readfirstlane(bB);
    const float tA = tind[bAu];
    const float tB = tind[bBu];

    const float* img0A = frames0 + (size_t)bAu * (HDIM * WDIM * CDIM);
    const float* img1A = frames1 + (size_t)bAu * (HDIM * WDIM * CDIM);
    const float* img0B = frames0 + (size_t)bBu * (HDIM * WDIM * CDIM);
    const float* img1B = frames1 + (size_t)bBu * (HDIM * WDIM * CDIM);

    // Phase 2: issue all 16 tap loads (4 groups x 4 loads)
    Taps t0A = bilinear_load(img0A, (float)yA - f0A.x, (float)xA - f0A.y);
    Taps t1A = bilinear_load(img1A, (float)yA - f1A.x, (float)xA - f1A.y);
    Taps t0B = bilinear_load(img0B, (float)yB - f0B.x, (float)xB - f0B.y);
    Taps t1B = bilinear_load(img1B, (float)yB - f1B.x, (float)xB - f1B.y);

    // Pin: no eval may be hoisted above / no load sunk below this point.
    __builtin_amdgcn_sched_barrier(0);

    // Phase 3: eval + store both
    float w0A = (1.0f - tA) * v0A, w1A = tA * v1A;
    float invA = __builtin_amdgcn_rcpf(w0A + w1A + 1e-12f);
    float w0B = (1.0f - tB) * v0B, w1B = tB * v1B;
    float invB = __builtin_amdgcn_rcpf(w0B + w1B + 1e-12f);

    float g0[3], g1[3];
    bilinear_eval(t0A, g0);
    bilinear_eval(t1A, g1);
    float* opA = out + 3 * pA;
    opA[0] = (w0A * g0[0] + w1A * g1[0]) * invA;
    opA[1] = (w0A * g0[1] + w1A * g1[1]) * invA;
    opA[2] = (w0A * g0[2] + w1A * g1[2]) * invA;

    bilinear_eval(t0B, g0);
    bilinear_eval(t1B, g1);
    float* opB = out + 3 * pB;
    opB[0] = (w0B * g0[0] + w1B * g1[0]) * invB;
    opB[1] = (w0B * g0[1] + w1B * g1[1]) * invB;
    opB[2] = (w0B * g0[2] + w1B * g1[2]) * invB;
}

extern "C" void kernel_launch(void* const* d_in, const int* in_sizes, int n_in,
                              void* d_out, int out_size, void* d_ws, size_t ws_size,
                              hipStream_t stream) {
    const float* frames0 = (const float*)d_in[0];
    const float* flow0   = (const float*)d_in[1];
    const float* vis0    = (const float*)d_in[2];
    const float* frames1 = (const float*)d_in[3];
    const float* flow1   = (const float*)d_in[4];
    const float* vis1    = (const float*)d_in[5];
    const float* tind    = (const float*)d_in[6];
    float* out = (float*)d_out;

    const int block = 256;
    const int grid = 8192;  // 2 px/thread, 4 residency rounds

    warp_interp_kernel<<<grid, block, 0, stream>>>(
        frames0, flow0, vis0, frames1, flow1, vis1, tind, out);
}

// Round 3
// 76.133 us; speedup vs baseline: 1.1898x; 1.1898x over previous
//
#include <hip/hip_runtime.h>

// Problem constants (B=16, H=512, W=512, C=3)
#define BDIM 16
#define HDIM 512
#define WDIM 512
#define CDIM 3

// Packed low-alignment vector types (frame pixel stride = 12 B).
struct __attribute__((aligned(4))) pf4 { float x, y, z, w; };
struct __attribute__((aligned(4))) pf2 { float x, y; };

struct Taps {
    pf4 a0; pf2 b0;   // row0: tl0 tl1 tl2 tr0 | tr1 tr2
    pf4 a1; pf2 b1;   // row1: bl0 bl1 bl2 br0 | br1 br2
    float ax, ay;
};

__device__ __forceinline__ Taps bilinear_load(
    const float* __restrict__ img, float qy, float qx)
{
    float fy = fminf(fmaxf(floorf(qy), 0.0f), (float)(HDIM - 2));
    float fx = fminf(fmaxf(floorf(qx), 0.0f), (float)(WDIM - 2));
    Taps tp;
    tp.ay = fminf(fmaxf(qy - fy, 0.0f), 1.0f);
    tp.ax = fminf(fmaxf(qx - fx, 0.0f), 1.0f);
    int iy = (int)fy;
    int ix = (int)fx;
    const float* r0 = img + ((size_t)iy * WDIM + ix) * CDIM;
    const float* r1 = r0 + WDIM * CDIM;
    tp.a0 = *reinterpret_cast<const pf4*>(r0);
    tp.b0 = *reinterpret_cast<const pf2*>(r0 + 4);
    tp.a1 = *reinterpret_cast<const pf4*>(r1);
    tp.b1 = *reinterpret_cast<const pf2*>(r1 + 4);
    return tp;
}

__device__ __forceinline__ void bilinear_eval(const Taps& t, float g[3])
{
    float tl[3] = {t.a0.x, t.a0.y, t.a0.z};
    float tr[3] = {t.a0.w, t.b0.x, t.b0.y};
    float bl[3] = {t.a1.x, t.a1.y, t.a1.z};
    float br[3] = {t.a1.w, t.b1.x, t.b1.y};
#pragma unroll
    for (int c = 0; c < CDIM; ++c) {
        float top = tl[c] + t.ax * (tr[c] - tl[c]);
        float bot = bl[c] + t.ax * (br[c] - bl[c]);
        g[c] = top + t.ay * (bot - top);
    }
}

// R17: exact revert to the verified-best R14 kernel (76.4 us).
// Post-mortems R15/R16: (a) 2px lane stride doubles per-instruction tap
// footprint -> more unique line-requests -> -13%; (b) nontemporal stream
// loads force warm-LLC-resident flows back to HBM -> -6%. Both confirm
// the binding resource is per-CU vector-memory line-request throughput:
// ~11.3 requests/px * 16384 px/CU ~= 185K cy ~= 77 us at 1 req/cy/CU,
// which R14's 76.4 us already meets. 8 gather taps/px are algorithmically
// irreducible (bilinear x 2 images, iid random flow kills lane sharing;
// LDS staging needs ~475 KB halo > 160 KB LDS).
// Structure: 8192 blocks x 256 thr, 2 px/thread dual chain 8 batches
// apart, XCD-contiguous swizzle (chunk 1024), 16-tap-load pin.
__global__ __launch_bounds__(256) void warp_interp_kernel(
    const float* __restrict__ frames0,  // [B,H,W,3]
    const float* __restrict__ flow0,    // [B,H,W,2]
    const float* __restrict__ vis0,     // [B,H,W,1]
    const float* __restrict__ frames1,  // [B,H,W,3]
    const float* __restrict__ flow1,    // [B,H,W,2]
    const float* __restrict__ vis1,     // [B,H,W,1]
    const float* __restrict__ tind,     // [B]
    float* __restrict__ out)            // [B,H,W,3]
{
    const int bid = blockIdx.x;
    const int swz = (bid & 7) * 1024 + (bid >> 3);  // bijective: 8192 = 8*1024
    const int idx = swz * 256 + threadIdx.x;        // 0 .. 2097151
    const int STRIDE = 8192 * 256;                  // 2097152 px = 8 batches

    const size_t pA = (size_t)idx;
    const size_t pB = pA + STRIDE;

    const int xA = (int)(pA & (WDIM - 1));
    const int yA = (int)((pA >> 9) & (HDIM - 1));
    const int bA = (int)(pA >> 18);
    const int xB = (int)(pB & (WDIM - 1));
    const int yB = (int)((pB >> 9) & (HDIM - 1));
    const int bB = (int)(pB >> 18);

    // Phase 1: stream loads for both pixels
    float2 f0A = *reinterpret_cast<const float2*>(flow0 + 2 * pA);
    float2 f1A = *reinterpret_cast<const float2*>(flow1 + 2 * pA);
    float2 f0B = *reinterpret_cast<const float2*>(flow0 + 2 * pB);
    float2 f1B = *reinterpret_cast<const float2*>(flow1 + 2 * pB);
    float v0A = vis0[pA], v1A = vis1[pA];
    float v0B = vis0[pB], v1B = vis1[pB];
    float tA = tind[bA], tB = tind[bB];

    const float* img0A = frames0 + (size_t)bA * HDIM * WDIM * CDIM;
    const float* img1A = frames1 + (size_t)bA * HDIM * WDIM * CDIM;
    const float* img0B = frames0 + (size_t)bB * HDIM * WDIM * CDIM;
    const float* img1B = frames1 + (size_t)bB * HDIM * WDIM * CDIM;

    // Phase 2: issue all 16 tap loads (4 groups x 4 loads)
    Taps t0A = bilinear_load(img0A, (float)yA - f0A.x, (float)xA - f0A.y);
    Taps t1A = bilinear_load(img1A, (float)yA - f1A.x, (float)xA - f1A.y);
    Taps t0B = bilinear_load(img0B, (float)yB - f0B.x, (float)xB - f0B.y);
    Taps t1B = bilinear_load(img1B, (float)yB - f1B.x, (float)xB - f1B.y);

    // Pin: no eval may be hoisted above / no load sunk below this point.
    __builtin_amdgcn_sched_barrier(0);

    // Phase 3: eval + store both
    float w0A = (1.0f - tA) * v0A, w1A = tA * v1A;
    float invA = __builtin_amdgcn_rcpf(w0A + w1A + 1e-12f);
    float w0B = (1.0f - tB) * v0B, w1B = tB * v1B;
    float invB = __builtin_amdgcn_rcpf(w0B + w1B + 1e-12f);

    float g0[3], g1[3];
    bilinear_eval(t0A, g0);
    bilinear_eval(t1A, g1);
    float* opA = out + 3 * pA;
    opA[0] = (w0A * g0[0] + w1A * g1[0]) * invA;
    opA[1] = (w0A * g0[1] + w1A * g1[1]) * invA;
    opA[2] = (w0A * g0[2] + w1A * g1[2]) * invA;

    bilinear_eval(t0B, g0);
    bilinear_eval(t1B, g1);
    float* opB = out + 3 * pB;
    opB[0] = (w0B * g0[0] + w1B * g1[0]) * invB;
    opB[1] = (w0B * g0[1] + w1B * g1[1]) * invB;
    opB[2] = (w0B * g0[2] + w1B * g1[2]) * invB;
}

extern "C" void kernel_launch(void* const* d_in, const int* in_sizes, int n_in,
                              void* d_out, int out_size, void* d_ws, size_t ws_size,
                              hipStream_t stream) {
    const float* frames0 = (const float*)d_in[0];
    const float* flow0   = (const float*)d_in[1];
    const float* vis0    = (const float*)d_in[2];
    const float* frames1 = (const float*)d_in[3];
    const float* flow1   = (const float*)d_in[4];
    const float* vis1    = (const float*)d_in[5];
    const float* tind    = (const float*)d_in[6];
    float* out = (float*)d_out;

    const int block = 256;
    const int grid = 8192;  // 2 px/thread, 4 residency rounds

    warp_interp_kernel<<<grid, block, 0, stream>>>(
        frames0, flow0, vis0, frames1, flow1, vis1, tind, out);
}